// Round 5
// baseline (597.269 us; speedup 1.0000x reference)
//
#include <hip/hip_runtime.h>
#include <stdint.h>

#define NTOK   4096
#define DMODEL 1024
#define HFF    4096
#define NEXP   8
#define BM     128
#define BK     64
#define MAX_MT 71        // max sum_e ceil(cnt_e/128) given sum cnt = 8192
#define SLOTS_PAD 9216

typedef unsigned int   u32;
typedef unsigned short u16;
typedef u32   u32x4  __attribute__((ext_vector_type(4)));
typedef short s16x8  __attribute__((ext_vector_type(8)));
typedef float f32x16 __attribute__((ext_vector_type(16)));

__device__ __forceinline__ u16 f2bf(float f) {
  u32 u = __builtin_bit_cast(u32, f);
  return (u16)((u + 0x7FFFu + ((u >> 16) & 1u)) >> 16);   // RNE, finite inputs
}
__device__ __forceinline__ float bf2f(u32 lo16) {
  return __builtin_bit_cast(float, lo16 << 16);
}

// async global->LDS, 16B per lane; LDS dest = wave-uniform base + lane*16
__device__ __forceinline__ void gld_lds16(const void* g, void* l) {
  __builtin_amdgcn_global_load_lds((const __attribute__((address_space(1))) void*)g,
                                   (__attribute__((address_space(3))) void*)l, 16, 0, 0);
}

// ---------------- x fp32 -> bf16 ----------------
__global__ void k_convert_x(const float* __restrict__ x, u16* __restrict__ xb) {
  int i = (blockIdx.x * 256 + threadIdx.x) * 4;
  float4 v = *(const float4*)(x + i);
  uint2 o;
  o.x = (u32)f2bf(v.x) | ((u32)f2bf(v.y) << 16);
  o.y = (u32)f2bf(v.z) | ((u32)f2bf(v.w) << 16);
  *(uint2*)(xb + i) = o;
}

// ---------------- W [K][N] fp32 -> fragment-ordered bf16 LDS-image tiles --------
// Tile (e,nt,kt) covers BK=64 k-rows x BN=NB32*32 n-cols. Image of NB32*256
// u32x4 entries: idx16 = ((k>>4)*NB32 + (n>>5))*64 + (n&31) + ((k>>3)&1)*32,
// element j of entry = W[kt*64 + (k&~7) + j][n]  (8 consecutive k per entry).
template <int NB32>
__global__ __launch_bounds__(256) void k_prearrange(
    const float* __restrict__ W, u32x4* __restrict__ Bp, int K, int N, int NT, int KT) {
  constexpr int BN  = NB32 * 32;
  constexpr int TPR = NB32 * 8;      // threads per k-row (BN/4 float4s)
  constexpr int RPP = 256 / TPR;     // k-rows per pass
  int tile = blockIdx.x;             // (e*NT + nt)*KT + kt
  int kt  = tile % KT; int rem = tile / KT;
  int nt  = rem % NT;  int e   = rem / NT;
  __shared__ u32x4 img4[NB32 * 256];
  u16* img = (u16*)img4;
  const int tid = threadIdx.x;
  const float* src = W + ((size_t)e * K + (size_t)kt * BK) * N + (size_t)nt * BN;
  const int n4 = (tid % TPR) * 4;
  const int k0 = tid / TPR;
#pragma unroll
  for (int p = 0; p < BK / RPP; ++p) {
    const int k = k0 + p * RPP;
    float4 v = *(const float4*)(src + (size_t)k * N + n4);
    u16 b[4] = { f2bf(v.x), f2bf(v.y), f2bf(v.z), f2bf(v.w) };
#pragma unroll
    for (int q = 0; q < 4; ++q) {
      const int n = n4 + q;
      const int idx16 = ((k >> 4) * NB32 + (n >> 5)) * 64 + (n & 31) + ((k >> 3) & 1) * 32;
      img[idx16 * 8 + (k & 7)] = b[q];
    }
  }
  __syncthreads();
  u32x4* outp = Bp + (size_t)tile * (NB32 * 256);
#pragma unroll
  for (int c = 0; c < NB32; ++c) outp[c * 256 + tid] = img4[c * 256 + tid];
}

// ---------------- gating: logits, top-2, softmax(2), counts ----------------
__global__ void k_gating(const float* __restrict__ x, const float* __restrict__ Wg,
                         const float* __restrict__ bg, int* __restrict__ top_idx,
                         float* __restrict__ top_w, int* __restrict__ counts) {
  int t = blockIdx.x, tid = threadIdx.x;
  float acc[NEXP];
#pragma unroll
  for (int e = 0; e < NEXP; ++e) acc[e] = 0.f;
  const float* xr = x + (size_t)t * DMODEL;
  for (int d = tid; d < DMODEL; d += 256) {
    float xv = xr[d];
    const float4* wg = (const float4*)(Wg + d * NEXP);
    float4 a = wg[0], b = wg[1];
    acc[0] += xv * a.x; acc[1] += xv * a.y; acc[2] += xv * a.z; acc[3] += xv * a.w;
    acc[4] += xv * b.x; acc[5] += xv * b.y; acc[6] += xv * b.z; acc[7] += xv * b.w;
  }
#pragma unroll
  for (int e = 0; e < NEXP; ++e)
#pragma unroll
    for (int off = 32; off; off >>= 1) acc[e] += __shfl_down(acc[e], off);
  __shared__ float red[4][NEXP];
  int w = tid >> 6;
  if ((tid & 63) == 0)
    for (int e = 0; e < NEXP; ++e) red[w][e] = acc[e];
  __syncthreads();
  if (tid == 0) {
    float v0 = -1e30f, v1 = -1e30f; int i0 = 0, i1 = 0;
    for (int e = 0; e < NEXP; ++e) {
      float l = red[0][e] + red[1][e] + red[2][e] + red[3][e] + bg[e];
      if (l > v0)      { v1 = v0; i1 = i0; v0 = l; i0 = e; }
      else if (l > v1) { v1 = l; i1 = e; }
    }
    float e1 = expf(v1 - v0);
    float w0 = 1.f / (1.f + e1);
    top_idx[2 * t] = i0; top_idx[2 * t + 1] = i1;
    top_w[2 * t] = w0;   top_w[2 * t + 1] = e1 * w0;
    atomicAdd(&counts[i0], 1); atomicAdd(&counts[i1], 1);
  }
}

// ------------ padded prefix offsets + compact live m-tile map ------------
__global__ void k_offsets(const int* __restrict__ counts, int* __restrict__ poffset,
                          int* __restrict__ mtile_e, int* __restrict__ mtile_lt) {
  if (threadIdx.x == 0 && blockIdx.x == 0) {
    int off = 0, nm = 0;
    for (int e = 0; e < NEXP; ++e) {
      poffset[e] = off;
      int nt = (counts[e] + BM - 1) / BM;
      for (int lt = 0; lt < nt; ++lt) { mtile_e[nm] = e; mtile_lt[nm] = lt; ++nm; }
      off += nt * BM;
    }
    for (; nm < MAX_MT; ++nm) { mtile_e[nm] = -1; mtile_lt[nm] = 0; }
  }
}

// ---------------- scatter tokens to expert slots ----------------
__global__ void k_scatter(const int* __restrict__ top_idx, const int* __restrict__ poffset,
                          int* __restrict__ cursor, int* __restrict__ tok_of_slot,
                          int* __restrict__ token_slot) {
  int t = blockIdx.x * 256 + threadIdx.x;
  if (t >= NTOK) return;
  for (int k = 0; k < 2; ++k) {
    int e = top_idx[2 * t + k];
    int p = atomicAdd(&cursor[e], 1);
    int slot = poffset[e] + p;
    tok_of_slot[slot] = t;
    token_slot[2 * t + k] = slot;
  }
}

// ---------------- grouped GEMM: C = act(A @ B + bias), bf16 in/out, fp32 acc ----
// BM=128, BN=128 (NB32=4), BK=64; 4 waves (wm=wv>>1, wn=wv&1), wave tile 64x64.
// T4 counted-vmcnt pipeline: 2 stages (8 loads each) in flight; per K-step
// s_waitcnt vmcnt(8) waits only the OLDEST 8 (current buffer), raw s_barrier
// (no drain), compute, barrier, re-stage. sched_barrier(0) pins ordering.
// Swizzle: XCD chunk = contiguous wgid range, mt-FASTEST inside the chunk so
// each XCD sweeps all m-tiles against a fixed n-slice (B stays L2-resident).
template <int NB32>
__global__ __launch_bounds__(256) void k_gemm(
    const u16* __restrict__ Asrc, int a_stride,
    const int* __restrict__ tok_of_slot,
    const u32x4* __restrict__ Bp,
    const float* __restrict__ bias, int Nfull, int NT, int K,
    const int* __restrict__ mtile_e, const int* __restrict__ mtile_lt,
    const int* __restrict__ poffset,
    u16* __restrict__ Cout, int c_stride, int do_gelu)
{
  constexpr int BN = NB32 * 32;
  constexpr int NI = NB32 / 2;       // n32 groups per wave
  constexpr int LPS = 4 + NB32;      // loads per stage per wave

  const u32 nwg  = gridDim.x;
  const u32 orig = blockIdx.x;
  const u32 g    = (orig & 7u) * (nwg >> 3) + (orig >> 3);
  const int mt = (int)(g % MAX_MT);
  const int nt = (int)(g / MAX_MT);

  const int e = mtile_e[mt];
  if (e < 0) return;
  const int base_slot = poffset[e] + mtile_lt[mt] * BM;

  __shared__ u32x4 As0[1024];        // 16KB each -> 64KB total
  __shared__ u32x4 As1[1024];
  __shared__ u32x4 Bs0[NB32 * 256];
  __shared__ u32x4 Bs1[NB32 * 256];

  const int tid  = threadIdx.x;
  const int lane = tid & 63;
  const int wv   = tid >> 6;
  const int wm   = wv >> 1;
  const int wn   = wv & 1;

  // per-lane A global source pointers for staging calls c=0..3 (m = c*32+(lane&31))
  const u16* aptr[4];
#pragma unroll
  for (int c = 0; c < 4; ++c) {
    const int m = c * 32 + (lane & 31);
    const int row = tok_of_slot ? tok_of_slot[base_slot + m] : (base_slot + m);
    aptr[c] = Asrc + (size_t)row * a_stride + wv * 16 + 8 * (lane >> 5);
  }
  const int KT = K / BK;
  const u32x4* btile = Bp + (size_t)(e * NT + nt) * KT * (NB32 * 256);
  const u32x4* bptr  = btile + wv * (NB32 * 64) + lane;

  f32x16 acc[2][NI] = {};

  auto stage = [&](u32x4* AS, u32x4* BS, int kt) {
#pragma unroll
    for (int c = 0; c < 4; ++c)
      gld_lds16(aptr[c] + kt * BK, &AS[(wv * 4 + c) * 64]);
#pragma unroll
    for (int c = 0; c < NB32; ++c)
      gld_lds16(bptr + (size_t)kt * (NB32 * 256) + c * 64, &BS[(wv * NB32 + c) * 64]);
  };
  auto compute = [&](const u32x4* AS, const u32x4* BS) {
#pragma unroll
    for (int kw = 0; kw < 4; ++kw) {
      const s16x8 a0 = __builtin_bit_cast(s16x8, AS[(kw * 4 + 2 * wm + 0) * 64 + lane]);
      const s16x8 a1 = __builtin_bit_cast(s16x8, AS[(kw * 4 + 2 * wm + 1) * 64 + lane]);
#pragma unroll
      for (int ni = 0; ni < NI; ++ni) {
        const s16x8 b = __builtin_bit_cast(s16x8, BS[(kw * NB32 + wn * NI + ni) * 64 + lane]);
        acc[0][ni] = __builtin_amdgcn_mfma_f32_32x32x16_bf16(a0, b, acc[0][ni], 0, 0, 0);
        acc[1][ni] = __builtin_amdgcn_mfma_f32_32x32x16_bf16(a1, b, acc[1][ni], 0, 0, 0);
      }
    }
  };

  stage(As0, Bs0, 0);                // LPS loads in flight
  stage(As1, Bs1, 1);                // 2*LPS in flight
  for (int kt = 0; kt < KT; ++kt) {
    // wait only the oldest LPS loads (current buffer); keep next stage in flight
    if (kt + 1 < KT) { asm volatile("s_waitcnt vmcnt(%0)" :: "n"(LPS) : "memory"); }
    else             { asm volatile("s_waitcnt vmcnt(0)"  ::            : "memory"); }
    __builtin_amdgcn_sched_barrier(0);
    __builtin_amdgcn_s_barrier();    // raw: no vmcnt drain
    __builtin_amdgcn_sched_barrier(0);
    if (kt & 1) compute(As1, Bs1); else compute(As0, Bs0);
    __builtin_amdgcn_sched_barrier(0);
    __builtin_amdgcn_s_barrier();    // all waves done reading this buffer
    __builtin_amdgcn_sched_barrier(0);
    if (kt + 2 < KT) {
      if (kt & 1) stage(As1, Bs1, kt + 2); else stage(As0, Bs0, kt + 2);
    }
  }

  // epilogue: C/D layout col=lane&31, row=(r&3)+8*(r>>2)+4*(lane>>5)  [m74/m101]
  const int rhi = (lane >> 5) * 4;
  const int col = lane & 31;
#pragma unroll
  for (int ni = 0; ni < NI; ++ni) {
    const int n = nt * BN + (wn * NI + ni) * 32 + col;
    const float bv = bias[(size_t)e * Nfull + n];
#pragma unroll
    for (int mi = 0; mi < 2; ++mi) {
#pragma unroll
      for (int r = 0; r < 16; ++r) {
        const int rowl = (2 * wm + mi) * 32 + (r & 3) + ((r >> 2) * 8) + rhi;
        float v = acc[mi][ni][r] + bv;
        if (do_gelu) v = 0.5f * v * (1.0f + erff(v * 0.70710678118654752f));
        Cout[(size_t)(base_slot + rowl) * c_stride + n] = f2bf(v);
      }
    }
  }
}

// ---------------- combine (top-2 weighted) + residual + LayerNorm ----------------
__global__ void k_combine_ln(const float* __restrict__ x, const u16* __restrict__ y,
                             const int* __restrict__ token_slot, const float* __restrict__ top_w,
                             const float* __restrict__ gamma, const float* __restrict__ beta,
                             float* __restrict__ out) {
  int t = blockIdx.x, tid = threadIdx.x;
  int s0 = token_slot[2 * t], s1 = token_slot[2 * t + 1];
  float w0 = top_w[2 * t], w1 = top_w[2 * t + 1];
  float4 xv = ((const float4*)(x + (size_t)t * DMODEL))[tid];
  uint2 a = ((const uint2*)(y + (size_t)s0 * DMODEL))[tid];
  uint2 b = ((const uint2*)(y + (size_t)s1 * DMODEL))[tid];
  float r0 = xv.x + w0 * bf2f(a.x & 0xffffu) + w1 * bf2f(b.x & 0xffffu);
  float r1 = xv.y + w0 * bf2f(a.x >> 16)     + w1 * bf2f(b.x >> 16);
  float r2 = xv.z + w0 * bf2f(a.y & 0xffffu) + w1 * bf2f(b.y & 0xffffu);
  float r3 = xv.w + w0 * bf2f(a.y >> 16)     + w1 * bf2f(b.y >> 16);
  float s  = r0 + r1 + r2 + r3;
  float sq = r0 * r0 + r1 * r1 + r2 * r2 + r3 * r3;
#pragma unroll
  for (int off = 32; off; off >>= 1) { s += __shfl_down(s, off); sq += __shfl_down(sq, off); }
  __shared__ float rs[4], rq[4];
  __shared__ float mu_s, rsig_s;
  int w = tid >> 6;
  if ((tid & 63) == 0) { rs[w] = s; rq[w] = sq; }
  __syncthreads();
  if (tid == 0) {
    float S = rs[0] + rs[1] + rs[2] + rs[3];
    float Q = rq[0] + rq[1] + rq[2] + rq[3];
    float mu  = S * (1.0f / DMODEL);
    float var = Q * (1.0f / DMODEL) - mu * mu;
    mu_s = mu; rsig_s = rsqrtf(var + 1e-5f);
  }
  __syncthreads();
  float mu = mu_s, rsig = rsig_s;
  float4 gv = ((const float4*)gamma)[tid];
  float4 bv = ((const float4*)beta)[tid];
  float4 o;
  o.x = (r0 - mu) * rsig * gv.x + bv.x;
  o.y = (r1 - mu) * rsig * gv.y + bv.y;
  o.z = (r2 - mu) * rsig * gv.z + bv.z;
  o.w = (r3 - mu) * rsig * gv.w + bv.w;
  ((float4*)(out + (size_t)t * DMODEL))[tid] = o;
}

// ---------------- launch ----------------
extern "C" void kernel_launch(void* const* d_in, const int* in_sizes, int n_in,
                              void* d_out, int out_size, void* d_ws, size_t ws_size,
                              hipStream_t stream) {
  const float* x     = (const float*)d_in[0];
  const float* Wg    = (const float*)d_in[1];
  const float* bg    = (const float*)d_in[2];
  const float* W1    = (const float*)d_in[3];
  const float* b1    = (const float*)d_in[4];
  const float* W2    = (const float*)d_in[5];
  const float* b2    = (const float*)d_in[6];
  const float* gamma = (const float*)d_in[7];
  const float* beta  = (const float*)d_in[8];
  float* out = (float*)d_out;

  char* ws = (char*)d_ws;
  size_t off = 0;
  auto alloc = [&](size_t bytes) {
    char* p = ws + off;
    off += (bytes + 255) & ~(size_t)255;
    return p;
  };
  u16*   xb   = (u16*)  alloc((size_t)NTOK * DMODEL * 2);        //   8.4 MB
  u32x4* Bp1  = (u32x4*)alloc((size_t)NEXP * DMODEL * HFF * 2);  //  67.1 MB
  u32x4* Bp2  = (u32x4*)alloc((size_t)NEXP * DMODEL * HFF * 2);  //  67.1 MB
  u16*   h    = (u16*)  alloc((size_t)SLOTS_PAD * HFF * 2);      //  75.5 MB
  u16*   yb   = (u16*)  alloc((size_t)SLOTS_PAD * DMODEL * 2);   //  18.9 MB
  int*   meta = (int*)  alloc((size_t)(24 + SLOTS_PAD + 2 * MAX_MT + 3 * 2 * NTOK + 8) * 4);
  int*   counts      = meta;
  int*   cursor      = counts + 8;
  int*   poffset     = cursor + 8;
  int*   tok_of_slot = poffset + 8;
  int*   mtile_e     = tok_of_slot + SLOTS_PAD;
  int*   mtile_lt    = mtile_e + MAX_MT;
  int*   token_slot  = mtile_lt + MAX_MT;
  int*   top_idx     = token_slot + 2 * NTOK;
  float* top_w       = (float*)(top_idx + 2 * NTOK);
  (void)ws_size; (void)in_sizes; (void)n_in; (void)out_size;

  // zero counts/cursor/poffset + tok_of_slot (pad rows -> token 0)
  hipMemsetAsync(meta, 0, (size_t)(24 + SLOTS_PAD) * 4, stream);

  k_convert_x<<<NTOK * DMODEL / 1024, 256, 0, stream>>>(x, xb);

  // BN=128 both: W1 NT=32, KT=16 ; W2 NT=8, KT=64
  k_prearrange<4><<<NEXP * (HFF / 128) * (DMODEL / BK), 256, 0, stream>>>(
      W1, Bp1, DMODEL, HFF, HFF / 128, DMODEL / BK);
  k_prearrange<4><<<NEXP * (DMODEL / 128) * (HFF / BK), 256, 0, stream>>>(
      W2, Bp2, HFF, DMODEL, DMODEL / 128, HFF / BK);

  k_gating<<<NTOK, 256, 0, stream>>>(x, Wg, bg, top_idx, top_w, counts);
  k_offsets<<<1, 1, 0, stream>>>(counts, poffset, mtile_e, mtile_lt);
  k_scatter<<<NTOK / 256, 256, 0, stream>>>(top_idx, poffset, cursor, tok_of_slot, token_slot);

  // GEMM1: 32 nt x 71 mt = 2272 blocks (2272 = 8*284)
  k_gemm<4><<<(HFF / 128) * MAX_MT, 256, 0, stream>>>(
      xb, DMODEL, tok_of_slot, Bp1, b1, HFF, HFF / 128, DMODEL,
      mtile_e, mtile_lt, poffset, h, HFF, 1);
  // GEMM2: 8 nt x 71 mt = 568 blocks (568 = 8*71)
  k_gemm<4><<<(DMODEL / 128) * MAX_MT, 256, 0, stream>>>(
      h, HFF, nullptr, Bp2, b2, DMODEL, DMODEL / 128, HFF,
      mtile_e, mtile_lt, poffset, yb, DMODEL, 0);

  k_combine_ln<<<NTOK, 256, 0, stream>>>(x, yb, token_slot, top_w, gamma, beta, out);
}

// Round 6
// 538.407 us; speedup vs baseline: 1.1093x; 1.1093x over previous
//
#include <hip/hip_runtime.h>
#include <stdint.h>

#define NTOK   4096
#define DMODEL 1024
#define HFF    4096
#define NEXP   8
#define BM     128
#define BN     128
#define BK     64
#define MAX_MT 71        // max sum_e ceil(cnt_e/128) given sum cnt = 8192
#define SLOTS_PAD 9216

typedef unsigned int   u32;
typedef unsigned short u16;
typedef u32   u32x4  __attribute__((ext_vector_type(4)));
typedef short s16x8  __attribute__((ext_vector_type(8)));
typedef float f32x4  __attribute__((ext_vector_type(4)));

__device__ __forceinline__ u16 f2bf(float f) {
  u32 u = __builtin_bit_cast(u32, f);
  return (u16)((u + 0x7FFFu + ((u >> 16) & 1u)) >> 16);   // RNE, finite inputs
}
__device__ __forceinline__ float bf2f(u32 lo16) {
  return __builtin_bit_cast(float, lo16 << 16);
}

// async global->LDS, 16B per lane; LDS dest = wave-uniform base + lane*16
__device__ __forceinline__ void gld_lds16(const void* g, void* l) {
  __builtin_amdgcn_global_load_lds((const __attribute__((address_space(1))) void*)g,
                                   (__attribute__((address_space(3))) void*)l, 16, 0, 0);
}

// ---------------- x fp32 -> bf16 ----------------
__global__ void k_convert_x(const float* __restrict__ x, u16* __restrict__ xb) {
  int i = (blockIdx.x * 256 + threadIdx.x) * 4;
  float4 v = *(const float4*)(x + i);
  uint2 o;
  o.x = (u32)f2bf(v.x) | ((u32)f2bf(v.y) << 16);
  o.y = (u32)f2bf(v.z) | ((u32)f2bf(v.w) << 16);
  *(uint2*)(xb + i) = o;
}

// ------- W [K][N] fp32 -> 16x16x32-fragment-ordered bf16 LDS-image tiles -------
// Tile (e,nt,kt) covers BK=64 k x BN=128 n. Image = 1024 u32x4 entries:
//   entry g*64+l, g = (k>>5)*8 + (n>>4), l = ((k>>3)&3)*16 + (n&15)
//   element j (k&7): W[kt*64 + k][nt*128 + n] with k = (g>>3)*32 + (l>>4)*8 + j
__global__ __launch_bounds__(256) void k_prearrange(
    const float* __restrict__ W, u32x4* __restrict__ Bp, int K, int N, int NT, int KT) {
  int tile = blockIdx.x;             // (e*NT + nt)*KT + kt
  int kt  = tile % KT; int rem = tile / KT;
  int nt  = rem % NT;  int e   = rem / NT;
  __shared__ u32x4 img4[1024];       // 16KB
  u16* img = (u16*)img4;
  const int tid = threadIdx.x;
  const float* src = W + ((size_t)e * K + (size_t)kt * BK) * N + (size_t)nt * BN;
  const int n4 = (tid & 31) * 4;     // local n of this thread's float4
  const int k0 = tid >> 5;           // base local k 0..7
#pragma unroll
  for (int p = 0; p < 8; ++p) {
    const int k = k0 + p * 8;
    float4 v = *(const float4*)(src + (size_t)k * N + n4);
    u16 b[4] = { f2bf(v.x), f2bf(v.y), f2bf(v.z), f2bf(v.w) };
#pragma unroll
    for (int q = 0; q < 4; ++q) {
      const int n = n4 + q;
      const int idx16 = ((k >> 5) * 8 + (n >> 4)) * 64 + ((k >> 3) & 3) * 16 + (n & 15);
      img[idx16 * 8 + (k & 7)] = b[q];
    }
  }
  __syncthreads();
  u32x4* outp = Bp + (size_t)tile * 1024;
#pragma unroll
  for (int c = 0; c < 4; ++c) outp[c * 256 + tid] = img4[c * 256 + tid];
}

// ---------------- gating: logits, top-2, softmax(2), counts ----------------
__global__ void k_gating(const float* __restrict__ x, const float* __restrict__ Wg,
                         const float* __restrict__ bg, int* __restrict__ top_idx,
                         float* __restrict__ top_w, int* __restrict__ counts) {
  int t = blockIdx.x, tid = threadIdx.x;
  float acc[NEXP];
#pragma unroll
  for (int e = 0; e < NEXP; ++e) acc[e] = 0.f;
  const float* xr = x + (size_t)t * DMODEL;
  for (int d = tid; d < DMODEL; d += 256) {
    float xv = xr[d];
    const float4* wg = (const float4*)(Wg + d * NEXP);
    float4 a = wg[0], b = wg[1];
    acc[0] += xv * a.x; acc[1] += xv * a.y; acc[2] += xv * a.z; acc[3] += xv * a.w;
    acc[4] += xv * b.x; acc[5] += xv * b.y; acc[6] += xv * b.z; acc[7] += xv * b.w;
  }
#pragma unroll
  for (int e = 0; e < NEXP; ++e)
#pragma unroll
    for (int off = 32; off; off >>= 1) acc[e] += __shfl_down(acc[e], off);
  __shared__ float red[4][NEXP];
  int w = tid >> 6;
  if ((tid & 63) == 0)
    for (int e = 0; e < NEXP; ++e) red[w][e] = acc[e];
  __syncthreads();
  if (tid == 0) {
    float v0 = -1e30f, v1 = -1e30f; int i0 = 0, i1 = 0;
    for (int e = 0; e < NEXP; ++e) {
      float l = red[0][e] + red[1][e] + red[2][e] + red[3][e] + bg[e];
      if (l > v0)      { v1 = v0; i1 = i0; v0 = l; i0 = e; }
      else if (l > v1) { v1 = l; i1 = e; }
    }
    float e1 = expf(v1 - v0);
    float w0 = 1.f / (1.f + e1);
    top_idx[2 * t] = i0; top_idx[2 * t + 1] = i1;
    top_w[2 * t] = w0;   top_w[2 * t + 1] = e1 * w0;
    atomicAdd(&counts[i0], 1); atomicAdd(&counts[i1], 1);
  }
}

// ------------ padded prefix offsets + compact live m-tile map ------------
__global__ void k_offsets(const int* __restrict__ counts, int* __restrict__ poffset,
                          int* __restrict__ mtile_e, int* __restrict__ mtile_lt) {
  if (threadIdx.x == 0 && blockIdx.x == 0) {
    int off = 0, nm = 0;
    for (int e = 0; e < NEXP; ++e) {
      poffset[e] = off;
      int nt = (counts[e] + BM - 1) / BM;
      for (int lt = 0; lt < nt; ++lt) { mtile_e[nm] = e; mtile_lt[nm] = lt; ++nm; }
      off += nt * BM;
    }
    for (; nm < MAX_MT; ++nm) { mtile_e[nm] = -1; mtile_lt[nm] = 0; }
  }
}

// ---------------- scatter tokens to expert slots ----------------
__global__ void k_scatter(const int* __restrict__ top_idx, const int* __restrict__ poffset,
                          int* __restrict__ cursor, int* __restrict__ tok_of_slot,
                          int* __restrict__ token_slot) {
  int t = blockIdx.x * 256 + threadIdx.x;
  if (t >= NTOK) return;
  for (int k = 0; k < 2; ++k) {
    int e = top_idx[2 * t + k];
    int p = atomicAdd(&cursor[e], 1);
    int slot = poffset[e] + p;
    tok_of_slot[slot] = t;
    token_slot[2 * t + k] = slot;
  }
}

// ---------------- grouped GEMM: C = act(A @ B + bias), bf16 in/out, fp32 acc ----
// m97 configuration: 128x128xBK64 tile, 4 waves (2x2), mfma_f32_16x16x32_bf16,
// per-wave acc[4][4] (wave tile 64x64). 0.5 KB LDS-read per MFMA (vs 1.0 for
// the 32x32 acc[2][2] variant that was LDS-read-BW-bound at ~16% MfmaUtil).
// Single-buffered 32KB LDS, 2x __syncthreads per K-step; multi-block overlap
// (~3 blocks/CU) hides the staging drain, as in m97 (874 TF measured).
// A image entry g = k32*8 + m16grp; lane l: row m16grp*16+(l&15),
//   k k32*32+(l>>4)*8 (+j). B image identical with n16grp.
__global__ __launch_bounds__(256) void k_gemm(
    const u16* __restrict__ Asrc, int a_stride,
    const int* __restrict__ tok_of_slot,
    const u32x4* __restrict__ Bp,
    const float* __restrict__ bias, int Nfull, int NT, int K,
    const int* __restrict__ mtile_e, const int* __restrict__ mtile_lt,
    const int* __restrict__ poffset,
    u16* __restrict__ Cout, int c_stride, int do_gelu)
{
  const u32 nwg  = gridDim.x;
  const u32 orig = blockIdx.x;
  const u32 g    = (orig & 7u) * (nwg >> 3) + (orig >> 3);  // XCD chunks, mt-fastest
  const int mt = (int)(g % MAX_MT);
  const int nt = (int)(g / MAX_MT);

  const int e = mtile_e[mt];
  if (e < 0) return;
  const int base_slot = poffset[e] + mtile_lt[mt] * BM;

  __shared__ u32x4 As[1024];         // 16KB
  __shared__ u32x4 Bs[1024];         // 16KB

  const int tid  = threadIdx.x;
  const int lane = tid & 63;
  const int wv   = tid >> 6;
  const int wm   = wv >> 1;
  const int wn   = wv & 1;

  // A staging pointers: call c stages entry group gA = wv*4+c
  //   m16grp = gA&7, k32 = gA>>3; lane l: row m16grp*16+(l&15), k k32*32+(l>>4)*8
  const u16* aptr[4];
#pragma unroll
  for (int c = 0; c < 4; ++c) {
    const int gA = wv * 4 + c;
    const int m = (gA & 7) * 16 + (lane & 15);
    const int row = tok_of_slot ? tok_of_slot[base_slot + m] : (base_slot + m);
    aptr[c] = Asrc + (size_t)row * a_stride + (gA >> 3) * 32 + (lane >> 4) * 8;
  }
  const int KT = K / BK;
  const u32x4* btile = Bp + (size_t)(e * NT + nt) * KT * 1024;
  const u32x4* bptr  = btile + wv * 256 + lane;   // call c adds c*64

  f32x4 acc[4][4] = {};

  for (int kt = 0; kt < KT; ++kt) {
#pragma unroll
    for (int c = 0; c < 4; ++c)
      gld_lds16(aptr[c] + kt * BK, &As[(wv * 4 + c) * 64]);
#pragma unroll
    for (int c = 0; c < 4; ++c)
      gld_lds16(bptr + (size_t)kt * 1024 + c * 64, &Bs[(wv * 4 + c) * 64]);
    __syncthreads();                 // images complete (vmcnt drained)
#pragma unroll
    for (int k32 = 0; k32 < 2; ++k32) {
      s16x8 a[4], b[4];
#pragma unroll
      for (int mi = 0; mi < 4; ++mi)
        a[mi] = __builtin_bit_cast(s16x8, As[(k32 * 8 + wm * 4 + mi) * 64 + lane]);
#pragma unroll
      for (int ni = 0; ni < 4; ++ni)
        b[ni] = __builtin_bit_cast(s16x8, Bs[(k32 * 8 + wn * 4 + ni) * 64 + lane]);
#pragma unroll
      for (int mi = 0; mi < 4; ++mi)
#pragma unroll
        for (int ni = 0; ni < 4; ++ni)
          acc[mi][ni] = __builtin_amdgcn_mfma_f32_16x16x32_bf16(a[mi], b[ni], acc[mi][ni], 0, 0, 0);
    }
    __syncthreads();                 // reads done before next overwrite
  }

  // epilogue: 16x16 C/D layout col=lane&15, row=(lane>>4)*4+r  [m89/m91]
  const int rbase = (lane >> 4) * 4;
  const int col = lane & 15;
#pragma unroll
  for (int ni = 0; ni < 4; ++ni) {
    const int n = nt * BN + wn * 64 + ni * 16 + col;
    const float bv = bias[(size_t)e * Nfull + n];
#pragma unroll
    for (int mi = 0; mi < 4; ++mi) {
#pragma unroll
      for (int r = 0; r < 4; ++r) {
        const int rowl = wm * 64 + mi * 16 + rbase + r;
        float v = acc[mi][ni][r] + bv;
        if (do_gelu) v = 0.5f * v * (1.0f + erff(v * 0.70710678118654752f));
        Cout[(size_t)(base_slot + rowl) * c_stride + n] = f2bf(v);
      }
    }
  }
}

// ---------------- combine (top-2 weighted) + residual + LayerNorm ----------------
__global__ void k_combine_ln(const float* __restrict__ x, const u16* __restrict__ y,
                             const int* __restrict__ token_slot, const float* __restrict__ top_w,
                             const float* __restrict__ gamma, const float* __restrict__ beta,
                             float* __restrict__ out) {
  int t = blockIdx.x, tid = threadIdx.x;
  int s0 = token_slot[2 * t], s1 = token_slot[2 * t + 1];
  float w0 = top_w[2 * t], w1 = top_w[2 * t + 1];
  float4 xv = ((const float4*)(x + (size_t)t * DMODEL))[tid];
  uint2 a = ((const uint2*)(y + (size_t)s0 * DMODEL))[tid];
  uint2 b = ((const uint2*)(y + (size_t)s1 * DMODEL))[tid];
  float r0 = xv.x + w0 * bf2f(a.x & 0xffffu) + w1 * bf2f(b.x & 0xffffu);
  float r1 = xv.y + w0 * bf2f(a.x >> 16)     + w1 * bf2f(b.x >> 16);
  float r2 = xv.z + w0 * bf2f(a.y & 0xffffu) + w1 * bf2f(b.y & 0xffffu);
  float r3 = xv.w + w0 * bf2f(a.y >> 16)     + w1 * bf2f(b.y >> 16);
  float s  = r0 + r1 + r2 + r3;
  float sq = r0 * r0 + r1 * r1 + r2 * r2 + r3 * r3;
#pragma unroll
  for (int off = 32; off; off >>= 1) { s += __shfl_down(s, off); sq += __shfl_down(sq, off); }
  __shared__ float rs[4], rq[4];
  __shared__ float mu_s, rsig_s;
  int w = tid >> 6;
  if ((tid & 63) == 0) { rs[w] = s; rq[w] = sq; }
  __syncthreads();
  if (tid == 0) {
    float S = rs[0] + rs[1] + rs[2] + rs[3];
    float Q = rq[0] + rq[1] + rq[2] + rq[3];
    float mu  = S * (1.0f / DMODEL);
    float var = Q * (1.0f / DMODEL) - mu * mu;
    mu_s = mu; rsig_s = rsqrtf(var + 1e-5f);
  }
  __syncthreads();
  float mu = mu_s, rsig = rsig_s;
  float4 gv = ((const float4*)gamma)[tid];
  float4 bv = ((const float4*)beta)[tid];
  float4 o;
  o.x = (r0 - mu) * rsig * gv.x + bv.x;
  o.y = (r1 - mu) * rsig * gv.y + bv.y;
  o.z = (r2 - mu) * rsig * gv.z + bv.z;
  o.w = (r3 - mu) * rsig * gv.w + bv.w;
  ((float4*)(out + (size_t)t * DMODEL))[tid] = o;
}

// ---------------- launch ----------------
extern "C" void kernel_launch(void* const* d_in, const int* in_sizes, int n_in,
                              void* d_out, int out_size, void* d_ws, size_t ws_size,
                              hipStream_t stream) {
  const float* x     = (const float*)d_in[0];
  const float* Wg    = (const float*)d_in[1];
  const float* bg    = (const float*)d_in[2];
  const float* W1    = (const float*)d_in[3];
  const float* b1    = (const float*)d_in[4];
  const float* W2    = (const float*)d_in[5];
  const float* b2    = (const float*)d_in[6];
  const float* gamma = (const float*)d_in[7];
  const float* beta  = (const float*)d_in[8];
  float* out = (float*)d_out;

  char* ws = (char*)d_ws;
  size_t off = 0;
  auto alloc = [&](size_t bytes) {
    char* p = ws + off;
    off += (bytes + 255) & ~(size_t)255;
    return p;
  };
  u16*   xb   = (u16*)  alloc((size_t)NTOK * DMODEL * 2);        //   8.4 MB
  u32x4* Bp1  = (u32x4*)alloc((size_t)NEXP * DMODEL * HFF * 2);  //  67.1 MB
  u32x4* Bp2  = (u32x4*)alloc((size_t)NEXP * DMODEL * HFF * 2);  //  67.1 MB
  u16*   h    = (u16*)  alloc((size_t)SLOTS_PAD * HFF * 2);      //  75.5 MB
  u16*   yb   = (u16*)  alloc((size_t)SLOTS_PAD * DMODEL * 2);   //  18.9 MB
  int*   meta = (int*)  alloc((size_t)(24 + SLOTS_PAD + 2 * MAX_MT + 3 * 2 * NTOK + 8) * 4);
  int*   counts      = meta;
  int*   cursor      = counts + 8;
  int*   poffset     = cursor + 8;
  int*   tok_of_slot = poffset + 8;
  int*   mtile_e     = tok_of_slot + SLOTS_PAD;
  int*   mtile_lt    = mtile_e + MAX_MT;
  int*   token_slot  = mtile_lt + MAX_MT;
  int*   top_idx     = token_slot + 2 * NTOK;
  float* top_w       = (float*)(top_idx + 2 * NTOK);
  (void)ws_size; (void)in_sizes; (void)n_in; (void)out_size;

  // zero counts/cursor/poffset + tok_of_slot (pad rows -> token 0)
  hipMemsetAsync(meta, 0, (size_t)(24 + SLOTS_PAD) * 4, stream);

  k_convert_x<<<NTOK * DMODEL / 1024, 256, 0, stream>>>(x, xb);

  // BN=128 both: W1 NT=32, KT=16 ; W2 NT=8, KT=64
  k_prearrange<<<NEXP * (HFF / 128) * (DMODEL / BK), 256, 0, stream>>>(
      W1, Bp1, DMODEL, HFF, HFF / 128, DMODEL / BK);
  k_prearrange<<<NEXP * (DMODEL / 128) * (HFF / BK), 256, 0, stream>>>(
      W2, Bp2, HFF, DMODEL, DMODEL / 128, HFF / BK);

  k_gating<<<NTOK, 256, 0, stream>>>(x, Wg, bg, top_idx, top_w, counts);
  k_offsets<<<1, 1, 0, stream>>>(counts, poffset, mtile_e, mtile_lt);
  k_scatter<<<NTOK / 256, 256, 0, stream>>>(top_idx, poffset, cursor, tok_of_slot, token_slot);

  // GEMM1: 32 nt x 71 mt = 2272 blocks (8*284)
  k_gemm<<<(HFF / 128) * MAX_MT, 256, 0, stream>>>(
      xb, DMODEL, tok_of_slot, Bp1, b1, HFF, HFF / 128, DMODEL,
      mtile_e, mtile_lt, poffset, h, HFF, 1);
  // GEMM2: 8 nt x 71 mt = 568 blocks (8*71)
  k_gemm<<<(DMODEL / 128) * MAX_MT, 256, 0, stream>>>(
      h, HFF, nullptr, Bp2, b2, DMODEL, DMODEL / 128, HFF,
      mtile_e, mtile_lt, poffset, yb, DMODEL, 0);

  k_combine_ln<<<NTOK, 256, 0, stream>>>(x, yb, token_slot, top_w, gamma, beta, out);
}